// Round 1
// baseline (173.815 us; speedup 1.0000x reference)
//
#include <hip/hip_runtime.h>
#include <stdint.h>
#include <math.h>

#define BATCH 16
#define NNODE 2048
#define DDIM  64
#define NEDGE 32768
#define SEG   32            // slots per quarter-scan segment (mean 8; P(>32)~1e-11)
#define SLOTS 128           // 4*SEG slots per row
#define NROWS (BATCH*NNODE) // 32768
#define RPB   128           // rows per k_build block (512-thread blocks)

// ---------------- kernel 1: LDS-bucketed edge build (quarter-scan) ------
// (verbatim from previous round)
__global__ void k_build(const int* __restrict__ ei, const float* __restrict__ m,
                        uint32_t* __restrict__ cnt4, uint2* __restrict__ entries) {
    __shared__ uint32_t cntS[RPB];
    __shared__ uint32_t keyS[RPB][SEG];   // col | prio<<11
    __shared__ float    valS[RPB][SEG];

    int b  = blockIdx.x & 15;             // batch (XCD-pinned)
    int gh = blockIdx.x >> 4;             // 0..63: row-group*4 + quarter
    int r0 = (gh >> 2) * RPB;             // first owned row
    int q  = gh & 3;                      // which quarter of the edge list
    int t  = threadIdx.x;                 // 0..511

    if (t < RPB) cntS[t] = 0u;
    __syncthreads();

    const int*   eb = ei + (size_t)b * 2 * NEDGE;
    const float* mb = m  + (size_t)b * NEDGE;
    int e0 = q * (NEDGE / 4);

    for (int i = 0; i < 4; ++i) {                  // 4 x 2048 edges (quarter)
        int e4 = e0 + i * 2048 + t * 4;
        int4   s4 = *(const int4*)(eb + e4);
        int4   d4 = *(const int4*)(eb + NEDGE + e4);
        float4 m4 = *(const float4*)(mb + e4);
        #pragma unroll
        for (int j = 0; j < 4; ++j) {
            int   src = j == 0 ? s4.x : j == 1 ? s4.y : j == 2 ? s4.z : s4.w;
            int   dst = j == 0 ? d4.x : j == 1 ? d4.y : j == 2 ? d4.z : d4.w;
            float mv  = j == 0 ? m4.x : j == 1 ? m4.y : j == 2 ? m4.z : m4.w;
            int e  = e4 + j;
            int rs = src - r0;
            if ((unsigned)rs < RPB) {              // row src, col dst, prio e
                uint32_t p = atomicAdd(&cntS[rs], 1u);
                if (p < SEG) { keyS[rs][p] = (uint32_t)dst | ((uint32_t)e << 11); valS[rs][p] = mv; }
            }
            int rd = dst - r0;
            if ((unsigned)rd < RPB) {              // row dst, col src, prio E+e
                uint32_t p = atomicAdd(&cntS[rd], 1u);
                if (p < SEG) { keyS[rd][p] = (uint32_t)src | ((uint32_t)(NEDGE + e) << 11); valS[rd][p] = mv; }
            }
        }
    }
    __syncthreads();

    // coalesced write-out: 8 waves x 16 rows; lanes 0-31 row 2rr, 32-63 row 2rr+1
    int lane = t & 63;
    int wid  = t >> 6;                    // 0..7
    int pos  = lane & 31;
    int sub  = lane >> 5;
    for (int rr = 0; rr < 8; ++rr) {
        int r  = wid * 16 + rr * 2 + sub;
        int rg = b * NNODE + r0 + r;
        int k  = (int)min(cntS[r], (uint32_t)SEG);
        size_t base = (size_t)rg * SLOTS + q * SEG;
        if (pos < k)
            entries[base + pos] = make_uint2(keyS[r][pos], __float_as_uint(valS[r][pos]));
        if (pos == 0) cnt4[rg * 4 + q] = (uint32_t)k;
    }
}

// ---------------- kernel 2: per-row dedupe + degree + compaction --------
// (verbatim from previous round)
__global__ void k_dedupe(const uint32_t* __restrict__ cnt4, uint2* __restrict__ entries,
                         uint32_t* __restrict__ cnt_fin,
                         float* __restrict__ dis, float* __restrict__ self) {
    int b    = blockIdx.x & 15;
    int w    = b * NNODE + (blockIdx.x >> 4) * 4 + (threadIdx.x >> 6);
    int lane = threadIdx.x & 63;
    uint4 kq = ((const uint4*)cnt4)[w];
    int k0 = (int)kq.x, k1 = (int)kq.y, k2 = (int)kq.z, k3 = (int)kq.w;
    size_t base = (size_t)w * SLOTS;
    int pos = lane & 31;
    int klo = (lane < 32) ? k0 : k1;
    int khi = (lane < 32) ? k2 : k3;

    uint32_t key0 = 0u, key1 = 0u;
    float v0 = 0.f, v1 = 0.f;
    bool a0 = pos < klo;
    bool a1 = pos < khi;
    if (a0) { uint2 kv = entries[base + lane];      key0 = kv.x; v0 = __uint_as_float(kv.y); }
    if (a1) { uint2 kv = entries[base + 64 + lane]; key1 = kv.x; v1 = __uint_as_float(kv.y); }
    uint32_t c0 = key0 & 2047u, p0 = key0 >> 11;
    uint32_t c1 = key1 & 2047u, p1 = key1 >> 11;

    #define KILL(ks) { uint32_t cs = (ks) & 2047u, ps = (ks) >> 11; \
        a0 = a0 && !((c0 == cs) && (p0 < ps)); \
        a1 = a1 && !((c1 == cs) && (p1 < ps)); }
    for (int s = 0; s < k0; ++s) KILL(__builtin_amdgcn_readlane(key0, s))
    for (int s = 0; s < k1; ++s) KILL(__builtin_amdgcn_readlane(key0, 32 + s))
    for (int s = 0; s < k2; ++s) KILL(__builtin_amdgcn_readlane(key1, s))
    for (int s = 0; s < k3; ++s) KILL(__builtin_amdgcn_readlane(key1, 32 + s))
    #undef KILL

    float sum = (a0 ? v0 : 0.f) + (a1 ? v1 : 0.f);
    for (int off = 32; off; off >>= 1) sum += __shfl_xor(sum, off, 64);
    float deg = fmaxf(1.0f + sum, 1e-6f);          // +1: identity diagonal
    if (lane == 0) {
        float di = 1.0f / sqrtf(deg);
        dis[w]  = di;
        self[w] = di * di;
    }

    unsigned long long m0 = __ballot(a0);
    unsigned long long m1 = __ballot(a1);
    unsigned long long below = (1ull << lane) - 1ull;
    int n0 = __popcll(m0);
    if (a0) entries[base + __popcll(m0 & below)]      = make_uint2(key0, __float_as_uint(v0));
    if (a1) entries[base + n0 + __popcll(m1 & below)] = make_uint2(key1, __float_as_uint(v1));
    if (lane == 0) cnt_fin[w] = (uint32_t)(n0 + __popcll(m1));
}

// ---------------- kernel 3: fused SpMM + (X @ W^T) + optional GELU ------
// v2: 4 rows per wave. Halves wave count (8192 waves/launch), amortizes the
// WT ds_read over 4 FMAs (9 ops / 4 row-MACs vs 5 ops / 2), and interleaves
// gathers from 4 independent rows (16 loads in flight across 4 dependency-
// free chains). Per-row bounds kept exact via wave-uniform guards; invalid
// lanes carry col=0/w=0 so 4-granular tails are numerically free.
__global__ void k_layer(const float* __restrict__ Xin, const float* __restrict__ W,
                        float* __restrict__ Xout,
                        const uint32_t* __restrict__ cnt_fin, const uint2* __restrict__ entries,
                        const float* __restrict__ dis, const float* __restrict__ self,
                        int dogelu) {
    __shared__ float WT[64 * 65];     // WT[d*65+e] = W[e*64+d]; +1 pad: conflict-free
    int Lb = blockIdx.x;              // 2048 blocks
    int b  = Lb & 15;                 // batch -> XCD swizzle
    int rb = Lb >> 4;                 // 0..127
    int t  = threadIdx.x;

    #pragma unroll
    for (int i = 0; i < 16; ++i) {
        int idx = i * 256 + t;
        WT[(idx & 63) * 65 + (idx >> 6)] = W[idx];
    }
    __syncthreads();

    int lane = t & 63;
    int wid  = t >> 6;
    const float* Xb   = Xin + (size_t)b * NNODE * DDIM;
    const char*  Xc   = (const char*)Xb + lane * 4;
    const float* disB = dis + (b << 11);

    int row0 = rb * 16 + wid * 4;     // 4 rows per wave
    int rg0  = b * NNODE + row0;

    uint32_t offA[4], wAu[4];
    float acc0[4], acc1[4];
    int kk[4], kc[4];
    int kmax = 0;
    #pragma unroll
    for (int r = 0; r < 4; ++r) {
        int rg = rg0 + r;
        int k  = (int)cnt_fin[rg];
        kk[r] = k;
        size_t base = (size_t)rg * SLOTS;
        uint32_t kA = 0u, vA = 0u;
        if (lane < k) { uint2 kv = entries[base + lane]; kA = kv.x; vA = kv.y; }
        float dr  = disB[row0 + r];
        int   col = (int)(kA & 2047u);
        offA[r] = (uint32_t)col << 8;                 // byte offset = col*256
        wAu[r]  = __float_as_uint(__uint_as_float(vA) * dr * disB[col]);
        acc0[r] = self[rg] * Xb[(size_t)(row0 + r) * DDIM + lane];   // identity term
        acc1[r] = 0.f;
        int c = k < 64 ? k : 64;
        kc[r] = c;
        kmax = c > kmax ? c : kmax;
    }

    // main gather loop: 4 rows x 4 edges per iteration, loads grouped first
    for (int e = 0; e < kmax; e += 4) {
        float xv[4][4], wv[4][4];
        #pragma unroll
        for (int r = 0; r < 4; ++r) {
            if (e < kc[r]) {                          // wave-uniform guard
                #pragma unroll
                for (int j = 0; j < 4; ++j) {
                    uint32_t o = __builtin_amdgcn_readlane(offA[r], e + j);
                    wv[r][j] = __uint_as_float(__builtin_amdgcn_readlane(wAu[r], e + j));
                    xv[r][j] = *(const float*)(Xc + o);
                }
            }
        }
        #pragma unroll
        for (int r = 0; r < 4; ++r) {
            if (e < kc[r]) {
                acc0[r] = fmaf(wv[r][0], xv[r][0], acc0[r]);
                acc1[r] = fmaf(wv[r][1], xv[r][1], acc1[r]);
                acc0[r] = fmaf(wv[r][2], xv[r][2], acc0[r]);
                acc1[r] = fmaf(wv[r][3], xv[r][3], acc1[r]);
            }
        }
    }

    // rare tail: k > 64
    #pragma unroll
    for (int r = 0; r < 4; ++r) {
        int k = kk[r];
        if (k > 64) {
            int rg = rg0 + r;
            size_t base = (size_t)rg * SLOTS;
            uint32_t kB = 0u, vB = 0u;
            if (lane + 64 < k) { uint2 kv = entries[base + 64 + lane]; kB = kv.x; vB = kv.y; }
            float dr  = disB[row0 + r];
            int   col = (int)(kB & 2047u);
            uint32_t offB = (uint32_t)col << 8;
            uint32_t wBu  = __float_as_uint(__uint_as_float(vB) * dr * disB[col]);
            for (int e2 = 64; e2 < k; ++e2) {
                uint32_t o  = __builtin_amdgcn_readlane(offB, e2 - 64);
                float    wvv = __uint_as_float(__builtin_amdgcn_readlane(wBu, e2 - 64));
                acc1[r] = fmaf(wvv, *(const float*)(Xc + o), acc1[r]);
            }
        }
    }

    // fused W-multiply: one WT read serves 4 rows
    float s0 = acc0[0] + acc1[0];
    float s1 = acc0[1] + acc1[1];
    float s2 = acc0[2] + acc1[2];
    float s3 = acc0[3] + acc1[3];
    float y0 = 0.f, y1 = 0.f, y2 = 0.f, y3 = 0.f;
    #pragma unroll
    for (int d = 0; d < 64; ++d) {
        float wt = WT[d * 65 + lane];
        y0 = fmaf(__uint_as_float(__builtin_amdgcn_readlane(__float_as_uint(s0), d)), wt, y0);
        y1 = fmaf(__uint_as_float(__builtin_amdgcn_readlane(__float_as_uint(s1), d)), wt, y1);
        y2 = fmaf(__uint_as_float(__builtin_amdgcn_readlane(__float_as_uint(s2), d)), wt, y2);
        y3 = fmaf(__uint_as_float(__builtin_amdgcn_readlane(__float_as_uint(s3), d)), wt, y3);
    }
    if (dogelu) {
        y0 = 0.5f * y0 * (1.0f + erff(y0 * 0.70710678118654752440f));
        y1 = 0.5f * y1 * (1.0f + erff(y1 * 0.70710678118654752440f));
        y2 = 0.5f * y2 * (1.0f + erff(y2 * 0.70710678118654752440f));
        y3 = 0.5f * y3 * (1.0f + erff(y3 * 0.70710678118654752440f));
    }
    size_t ob = ((size_t)b * NNODE + row0) * DDIM + lane;
    Xout[ob]            = y0;
    Xout[ob + DDIM]     = y1;
    Xout[ob + 2 * DDIM] = y2;
    Xout[ob + 3 * DDIM] = y3;
}

// ---------------- launch ------------------------------------------------
extern "C" void kernel_launch(void* const* d_in, const int* in_sizes, int n_in,
                              void* d_out, int out_size, void* d_ws, size_t ws_size,
                              hipStream_t stream) {
    const float* H  = (const float*)d_in[0];   // (B,N,D) fp32
    const int*   ei = (const int*)d_in[1];     // (B,2,E) int32
    const float* m  = (const float*)d_in[2];   // (B,E) fp32
    const float* W  = (const float*)d_in[3];   // (L,D,D) fp32
    float* out = (float*)d_out;                // (B,N,D) fp32

    char* ws = (char*)d_ws;
    uint32_t* cnt4    = (uint32_t*)ws;                                        // 512 KB (4 counts/row)
    uint32_t* cnt_fin = (uint32_t*)(ws + (512 << 10));                        // 128 KB
    float*    dis     = (float*)(ws + (640 << 10));                           // 128 KB
    float*    self    = (float*)(ws + (768 << 10));                           // 128 KB
    uint2*    entries = (uint2*)(ws + (896 << 10));                           // 32768*128*8 = 32 MB
    float*    X2      = (float*)(ws + (896 << 10) + (size_t)NROWS * SLOTS * 8);  // 8 MB

    k_build <<<BATCH * (NNODE / RPB) * 4, 512, 0, stream>>>(ei, m, cnt4, entries);
    k_dedupe<<<NROWS / 4, 256, 0, stream>>>(cnt4, entries, cnt_fin, dis, self);
    k_layer <<<BATCH * (NNODE / 16), 256, 0, stream>>>(H,  W,        X2,  cnt_fin, entries, dis, self, 1);
    k_layer <<<BATCH * (NNODE / 16), 256, 0, stream>>>(X2, W + 4096, out, cnt_fin, entries, dis, self, 0);
}

// Round 2
// 145.803 us; speedup vs baseline: 1.1921x; 1.1921x over previous
//
#include <hip/hip_runtime.h>
#include <stdint.h>
#include <math.h>

#define BATCH 16
#define NNODE 2048
#define DDIM  64
#define NEDGE 32768
#define SEG   32            // slots per quarter-scan segment (mean 8; P(>32)~1e-11)
#define SLOTS 128           // 4*SEG slots per row
#define NROWS (BATCH*NNODE) // 32768
#define RPB   128           // rows per k_build block (512-thread blocks)

// ---------------- kernel 1: LDS-bucketed edge build (quarter-scan) ------
// (verbatim — known-good)
__global__ void k_build(const int* __restrict__ ei, const float* __restrict__ m,
                        uint32_t* __restrict__ cnt4, uint2* __restrict__ entries) {
    __shared__ uint32_t cntS[RPB];
    __shared__ uint32_t keyS[RPB][SEG];   // col | prio<<11
    __shared__ float    valS[RPB][SEG];

    int b  = blockIdx.x & 15;             // batch (XCD-pinned)
    int gh = blockIdx.x >> 4;             // 0..63: row-group*4 + quarter
    int r0 = (gh >> 2) * RPB;             // first owned row
    int q  = gh & 3;                      // which quarter of the edge list
    int t  = threadIdx.x;                 // 0..511

    if (t < RPB) cntS[t] = 0u;
    __syncthreads();

    const int*   eb = ei + (size_t)b * 2 * NEDGE;
    const float* mb = m  + (size_t)b * NEDGE;
    int e0 = q * (NEDGE / 4);

    for (int i = 0; i < 4; ++i) {                  // 4 x 2048 edges (quarter)
        int e4 = e0 + i * 2048 + t * 4;
        int4   s4 = *(const int4*)(eb + e4);
        int4   d4 = *(const int4*)(eb + NEDGE + e4);
        float4 m4 = *(const float4*)(mb + e4);
        #pragma unroll
        for (int j = 0; j < 4; ++j) {
            int   src = j == 0 ? s4.x : j == 1 ? s4.y : j == 2 ? s4.z : s4.w;
            int   dst = j == 0 ? d4.x : j == 1 ? d4.y : j == 2 ? d4.z : d4.w;
            float mv  = j == 0 ? m4.x : j == 1 ? m4.y : j == 2 ? m4.z : m4.w;
            int e  = e4 + j;
            int rs = src - r0;
            if ((unsigned)rs < RPB) {              // row src, col dst, prio e
                uint32_t p = atomicAdd(&cntS[rs], 1u);
                if (p < SEG) { keyS[rs][p] = (uint32_t)dst | ((uint32_t)e << 11); valS[rs][p] = mv; }
            }
            int rd = dst - r0;
            if ((unsigned)rd < RPB) {              // row dst, col src, prio E+e
                uint32_t p = atomicAdd(&cntS[rd], 1u);
                if (p < SEG) { keyS[rd][p] = (uint32_t)src | ((uint32_t)(NEDGE + e) << 11); valS[rd][p] = mv; }
            }
        }
    }
    __syncthreads();

    // coalesced write-out: 8 waves x 16 rows; lanes 0-31 row 2rr, 32-63 row 2rr+1
    int lane = t & 63;
    int wid  = t >> 6;                    // 0..7
    int pos  = lane & 31;
    int sub  = lane >> 5;
    for (int rr = 0; rr < 8; ++rr) {
        int r  = wid * 16 + rr * 2 + sub;
        int rg = b * NNODE + r0 + r;
        int k  = (int)min(cntS[r], (uint32_t)SEG);
        size_t base = (size_t)rg * SLOTS + q * SEG;
        if (pos < k)
            entries[base + pos] = make_uint2(keyS[r][pos], __float_as_uint(valS[r][pos]));
        if (pos == 0) cnt4[rg * 4 + q] = (uint32_t)k;
    }
}

// ---------------- kernel 2: per-row dedupe via LDS scatter-max ----------
// v2: replaces the O(k^2/64) serial readlane KILL loops with an O(1)/entry
// scatter-max: per-wave private 2048-slot LDS table; clear touched slots,
// atomicMax(tbl[col], prio), read back -> survivor iff tbl[col]==prio.
// Prios are unique, so this is exactly last-writer-wins (same semantics).
// Same wave executes its LDS ops in issue order; read-back is a dependent
// LDS read so the compiler inserts the lgkmcnt wait.
__global__ void k_dedupe(const uint32_t* __restrict__ cnt4, uint2* __restrict__ entries,
                         uint32_t* __restrict__ cnt_fin,
                         float* __restrict__ dis, float* __restrict__ self) {
    __shared__ uint32_t tbl[4][NNODE];    // 32 KB: one table per wave
    int b    = blockIdx.x & 15;
    int wv   = threadIdx.x >> 6;
    int w    = b * NNODE + (blockIdx.x >> 4) * 4 + wv;
    int lane = threadIdx.x & 63;
    uint32_t* T = tbl[wv];
    uint4 kq = ((const uint4*)cnt4)[w];
    int k0 = (int)kq.x, k1 = (int)kq.y, k2 = (int)kq.z, k3 = (int)kq.w;
    size_t base = (size_t)w * SLOTS;
    int pos = lane & 31;
    int klo = (lane < 32) ? k0 : k1;
    int khi = (lane < 32) ? k2 : k3;

    uint32_t key0 = 0u, key1 = 0u;
    float v0 = 0.f, v1 = 0.f;
    bool a0 = pos < klo;
    bool a1 = pos < khi;
    if (a0) { uint2 kv = entries[base + lane];      key0 = kv.x; v0 = __uint_as_float(kv.y); }
    if (a1) { uint2 kv = entries[base + 64 + lane]; key1 = kv.x; v1 = __uint_as_float(kv.y); }
    uint32_t c0 = key0 & 2047u, p0 = key0 >> 11;
    uint32_t c1 = key1 & 2047u, p1 = key1 >> 11;

    // clear only the touched slots (LDS is uninitialized garbage otherwise)
    if (a0) T[c0] = 0u;
    if (a1) T[c1] = 0u;
    // scatter-max the priorities
    if (a0) atomicMax(&T[c0], p0);
    if (a1) atomicMax(&T[c1], p1);
    // read back: survivor iff my prio won
    if (a0) a0 = (T[c0] == p0);
    if (a1) a1 = (T[c1] == p1);

    float sum = (a0 ? v0 : 0.f) + (a1 ? v1 : 0.f);
    for (int off = 32; off; off >>= 1) sum += __shfl_xor(sum, off, 64);
    float deg = fmaxf(1.0f + sum, 1e-6f);          // +1: identity diagonal
    if (lane == 0) {
        float di = 1.0f / sqrtf(deg);
        dis[w]  = di;
        self[w] = di * di;
    }

    unsigned long long m0 = __ballot(a0);
    unsigned long long m1 = __ballot(a1);
    unsigned long long below = (1ull << lane) - 1ull;
    int n0 = __popcll(m0);
    if (a0) entries[base + __popcll(m0 & below)]      = make_uint2(key0, __float_as_uint(v0));
    if (a1) entries[base + n0 + __popcll(m1 & below)] = make_uint2(key1, __float_as_uint(v1));
    if (lane == 0) cnt_fin[w] = (uint32_t)(n0 + __popcll(m1));
}

// ---------------- kernel 3: fused SpMM + (X @ W^T) + optional GELU ------
// (reverted to R0 verbatim: 2 rows/wave, 4096 blocks — best measured form)
__global__ void k_layer(const float* __restrict__ Xin, const float* __restrict__ W,
                        float* __restrict__ Xout,
                        const uint32_t* __restrict__ cnt_fin, const uint2* __restrict__ entries,
                        const float* __restrict__ dis, const float* __restrict__ self,
                        int dogelu) {
    __shared__ float WT[64 * 65];     // WT[d*65+e] = W[e*64+d]; +1 pad: conflict-free
    int Lb = blockIdx.x;              // 4096 blocks
    int b  = Lb & 15;                 // batch -> XCD swizzle
    int rb = Lb >> 4;
    int t  = threadIdx.x;

    #pragma unroll
    for (int i = 0; i < 16; ++i) {
        int idx = i * 256 + t;
        WT[(idx & 63) * 65 + (idx >> 6)] = W[idx];
    }
    __syncthreads();

    int lane = t & 63;
    int wid  = t >> 6;
    const float* Xb   = Xin + (size_t)b * NNODE * DDIM;
    const char*  Xc   = (const char*)Xb + lane * 4;
    const float* disB = dis + (b << 11);

    float accv[2];
    #pragma unroll
    for (int rr = 0; rr < 2; ++rr) {
        int row = rb * 8 + wid * 2 + rr;
        int rg  = b * NNODE + row;
        int k   = (int)cnt_fin[rg];
        size_t base = (size_t)rg * SLOTS;

        uint32_t kA = 0u, vA = 0u, kB = 0u, vB = 0u;
        if (lane < k)      { uint2 kv = entries[base + lane];      kA = kv.x; vA = kv.y; }
        if (lane + 64 < k) { uint2 kv = entries[base + 64 + lane]; kB = kv.x; vB = kv.y; }

        // in-lane normalization before broadcast: off = col*256, w = dr*val*dis[col]
        float dr = disB[row];
        int   colA = (int)(kA & 2047u);
        uint32_t offA = (uint32_t)colA << 8;
        uint32_t wAu  = __float_as_uint(__uint_as_float(vA) * dr * disB[colA]);
        int   colB = (int)(kB & 2047u);
        uint32_t offB = (uint32_t)colB << 8;
        uint32_t wBu  = __float_as_uint(__uint_as_float(vB) * dr * disB[colB]);

        float acc0 = self[rg] * Xb[(size_t)row * DDIM + lane];   // identity term
        float acc1 = 0.f, acc2 = 0.f, acc3 = 0.f;

        int k0 = k < 64 ? k : 64;
        int e = 0;
        for (; e + 16 <= k0; e += 16) {            // 16 loads in flight
            float xv0, xv1, xv2, xv3, xv4, xv5, xv6, xv7;
            float xv8, xv9, xva, xvb, xvc, xvd, xve, xvf;
            float w0, w1, w2, w3, w4, w5, w6, w7;
            float w8, w9, wa, wb, wc, wd, we, wf;
            #define G(idx, X, Wv) { \
                uint32_t o = __builtin_amdgcn_readlane(offA, e + idx); \
                Wv = __uint_as_float(__builtin_amdgcn_readlane(wAu, e + idx)); \
                X = *(const float*)(Xc + o); }
            G(0, xv0, w0)  G(1, xv1, w1)  G(2, xv2, w2)  G(3, xv3, w3)
            G(4, xv4, w4)  G(5, xv5, w5)  G(6, xv6, w6)  G(7, xv7, w7)
            G(8, xv8, w8)  G(9, xv9, w9)  G(10, xva, wa) G(11, xvb, wb)
            G(12, xvc, wc) G(13, xvd, wd) G(14, xve, we) G(15, xvf, wf)
            #undef G
            acc0 = fmaf(w0, xv0, acc0); acc1 = fmaf(w1, xv1, acc1);
            acc2 = fmaf(w2, xv2, acc2); acc3 = fmaf(w3, xv3, acc3);
            acc0 = fmaf(w4, xv4, acc0); acc1 = fmaf(w5, xv5, acc1);
            acc2 = fmaf(w6, xv6, acc2); acc3 = fmaf(w7, xv7, acc3);
            acc0 = fmaf(w8, xv8, acc0); acc1 = fmaf(w9, xv9, acc1);
            acc2 = fmaf(wa, xva, acc2); acc3 = fmaf(wb, xvb, acc3);
            acc0 = fmaf(wc, xvc, acc0); acc1 = fmaf(wd, xvd, acc1);
            acc2 = fmaf(we, xve, acc2); acc3 = fmaf(wf, xvf, acc3);
        }
        for (; e + 4 <= k0; e += 4) {
            uint32_t o0 = __builtin_amdgcn_readlane(offA, e);
            uint32_t o1 = __builtin_amdgcn_readlane(offA, e + 1);
            uint32_t o2 = __builtin_amdgcn_readlane(offA, e + 2);
            uint32_t o3 = __builtin_amdgcn_readlane(offA, e + 3);
            float w0 = __uint_as_float(__builtin_amdgcn_readlane(wAu, e));
            float w1 = __uint_as_float(__builtin_amdgcn_readlane(wAu, e + 1));
            float w2 = __uint_as_float(__builtin_amdgcn_readlane(wAu, e + 2));
            float w3 = __uint_as_float(__builtin_amdgcn_readlane(wAu, e + 3));
            acc0 = fmaf(w0, *(const float*)(Xc + o0), acc0);
            acc1 = fmaf(w1, *(const float*)(Xc + o1), acc1);
            acc2 = fmaf(w2, *(const float*)(Xc + o2), acc2);
            acc3 = fmaf(w3, *(const float*)(Xc + o3), acc3);
        }
        for (; e < k0; ++e) {
            uint32_t o = __builtin_amdgcn_readlane(offA, e);
            float wv = __uint_as_float(__builtin_amdgcn_readlane(wAu, e));
            acc0 = fmaf(wv, *(const float*)(Xc + o), acc0);
        }
        for (e = 64; e < k; ++e) {                 // rare tail (k>64)
            uint32_t o = __builtin_amdgcn_readlane(offB, e - 64);
            float wv = __uint_as_float(__builtin_amdgcn_readlane(wBu, e - 64));
            acc1 = fmaf(wv, *(const float*)(Xc + o), acc1);
        }
        accv[rr] = (acc0 + acc1) + (acc2 + acc3);
    }

    // fused W-multiply: one WT read serves both rows
    float sa = accv[0], sb = accv[1];
    float ya = 0.f, yb = 0.f;
    #pragma unroll
    for (int d = 0; d < 64; ++d) {
        float wt = WT[d * 65 + lane];
        ya = fmaf(__uint_as_float(__builtin_amdgcn_readlane(__float_as_uint(sa), d)), wt, ya);
        yb = fmaf(__uint_as_float(__builtin_amdgcn_readlane(__float_as_uint(sb), d)), wt, yb);
    }
    if (dogelu) {
        ya = 0.5f * ya * (1.0f + erff(ya * 0.70710678118654752440f));
        yb = 0.5f * yb * (1.0f + erff(yb * 0.70710678118654752440f));
    }
    int row0 = rb * 8 + wid * 2;
    Xout[((size_t)b * NNODE + row0)     * DDIM + lane] = ya;
    Xout[((size_t)b * NNODE + row0 + 1) * DDIM + lane] = yb;
}

// ---------------- launch ------------------------------------------------
extern "C" void kernel_launch(void* const* d_in, const int* in_sizes, int n_in,
                              void* d_out, int out_size, void* d_ws, size_t ws_size,
                              hipStream_t stream) {
    const float* H  = (const float*)d_in[0];   // (B,N,D) fp32
    const int*   ei = (const int*)d_in[1];     // (B,2,E) int32
    const float* m  = (const float*)d_in[2];   // (B,E) fp32
    const float* W  = (const float*)d_in[3];   // (L,D,D) fp32
    float* out = (float*)d_out;                // (B,N,D) fp32

    char* ws = (char*)d_ws;
    uint32_t* cnt4    = (uint32_t*)ws;                                        // 512 KB (4 counts/row)
    uint32_t* cnt_fin = (uint32_t*)(ws + (512 << 10));                        // 128 KB
    float*    dis     = (float*)(ws + (640 << 10));                           // 128 KB
    float*    self    = (float*)(ws + (768 << 10));                           // 128 KB
    uint2*    entries = (uint2*)(ws + (896 << 10));                           // 32768*128*8 = 32 MB
    float*    X2      = (float*)(ws + (896 << 10) + (size_t)NROWS * SLOTS * 8);  // 8 MB

    k_build <<<BATCH * (NNODE / RPB) * 4, 512, 0, stream>>>(ei, m, cnt4, entries);
    k_dedupe<<<NROWS / 4, 256, 0, stream>>>(cnt4, entries, cnt_fin, dis, self);
    k_layer <<<4096, 256, 0, stream>>>(H,  W,        X2,  cnt_fin, entries, dis, self, 1);
    k_layer <<<4096, 256, 0, stream>>>(X2, W + 4096, out, cnt_fin, entries, dis, self, 0);
}